// Round 16
// baseline (118.164 us; speedup 1.0000x reference)
//
#include <hip/hip_runtime.h>
#include <hip/hip_bf16.h>

#define CD 96
#define LROW 3136          // 56*56
#define QSCALE 0.17677669529663687f  // 1/sqrt(32)
#define LOG2E 1.4426950408889634f
#define MASKLOG2 -144.26950408889634f // -100 * log2(e)

using f32x4 = __attribute__((ext_vector_type(4))) float;
using bf8   = __attribute__((ext_vector_type(8))) short;

__device__ __forceinline__ short f2bf(float f) {
  union { float f; unsigned u; } v; v.f = f;
  unsigned r = v.u + 0x7fffu + ((v.u >> 16) & 1u);
  return (short)(r >> 16);
}
__device__ __forceinline__ float bf2f(unsigned short s) {
  return __uint_as_float((unsigned)s << 16);
}
__device__ __forceinline__ unsigned pack_bf2(float lo, float hi) {
  return (__float_as_uint(hi) & 0xffff0000u) | (__float_as_uint(lo) >> 16);
}
__device__ __forceinline__ unsigned pack_bf2r(float lo, float hi) {
  return ((unsigned)(unsigned short)f2bf(hi) << 16) | (unsigned short)f2bf(lo);
}
__device__ __forceinline__ float fast_exp2(float x) {
  return __builtin_amdgcn_exp2f(x);
}
// gelu tanh-approx via exp2: 0.5v(1+tanh(u)) = v*e/(e+1), e = exp(2u)
__device__ __forceinline__ float gelu_f(float v) {
  float u = 0.7978845608028654f * (v + 0.044715f * v * v * v);
  float e = fast_exp2(u * 2.8853900817779268f);  // 2*log2(e)
  return v * e * __builtin_amdgcn_rcpf(e + 1.f);
}

#define GLOAD_LDS16(src, dst) \
  __builtin_amdgcn_global_load_lds((const __attribute__((address_space(1))) void*)(src), \
                                   (__attribute__((address_space(3))) void*)(dst), 16, 0, 0)

// ---------------- fused weight convert (+ tail scalars) ----------------
__global__ __launch_bounds__(256) void cvt_all_kernel(
    const float* __restrict__ qkv2_w, const float* __restrict__ out_w,
    const float* __restrict__ fc1_w, const float* __restrict__ fc2_w,
    const float* __restrict__ qkv_w, const float* __restrict__ proj_w,
    short* __restrict__ dst,
    const int* __restrict__ Hp, const int* __restrict__ Wp,
    float* __restrict__ tail_out) {
  int idx = blockIdx.x * 256 + threadIdx.x;
  if (idx == 0) {
    tail_out[0] = (float)Hp[0];
    tail_out[1] = (float)Wp[0];
  }
  if (idx >= 165888) return;
  const float* W; int K, N, off;
  if (idx < 30720)       { W = qkv2_w; K = 96;  N = 288; off = idx; }
  else if (idx < 43008)  { W = out_w;  K = 96;  N = 96;  off = idx - 30720; }
  else if (idx < 79872)  { W = fc1_w;  K = 96;  N = 384; off = idx - 43008; }
  else if (idx < 129024) { W = fc2_w;  K = 384; N = 96;  off = idx - 79872; }
  else if (idx < 156672) { W = qkv_w;  K = 96;  N = 288; off = idx - 129024; }
  else                   { W = proj_w; K = 96;  N = 96;  off = idx - 156672; }
  int nr = off / K, kk = off - nr * K;
  float v = (nr < N) ? W[(size_t)kk * N + nr] : 0.f;
  dst[idx] = f2bf(v);
}

// ---------------- MFMA shifted-window attention, fused LN1 gather + LN-tb1 epilogue ----------------
__global__ __launch_bounds__(512) void win_attn_kernel(
    const float* __restrict__ xin,
    const float* __restrict__ n1s, const float* __restrict__ n1b,
    const short* __restrict__ wwin, const float* __restrict__ qkv_b,
    const short* __restrict__ wproj, const float* __restrict__ proj_b,
    const float* __restrict__ ln1s, const float* __restrict__ ln1b,
    float* __restrict__ x1, short* __restrict__ hb2) {
  __shared__ __align__(16) short Xs[64][104];
  __shared__ __align__(16) short Qs[3][64][40];
  __shared__ __align__(16) short Ks[3][64][40];
  __shared__ __align__(16) short Vt[3][32][72];
  __shared__ __align__(16) short Os[64][104];
  __shared__ __align__(16) short Ptw[8][16][72];
  __shared__ int cnt[64];
  __shared__ int gidx[49];

  int tid = threadIdx.x, lane = tid & 63, wid = tid >> 6;
  int lr = lane & 15, lg = lane >> 4;
  int b = blockIdx.x >> 6, w64 = blockIdx.x & 63;
  int wr = w64 >> 3, wc = w64 & 7;

  if (tid < 64) {
    if (tid < 49) {
      int i = tid / 7, j = tid % 7;
      int sh = wr * 7 + i, sw = wc * 7 + j;
      int hr = (sh < 49) ? 0 : ((sh < 53) ? 1 : 2);
      int wreg = (sw < 49) ? 0 : ((sw < 53) ? 1 : 2);
      cnt[tid] = hr * 3 + wreg;
      gidx[tid] = ((sh + 3) % 56) * 56 + ((sw + 3) % 56);
    } else {
      cnt[tid] = -1;
    }
  }
  __syncthreads();

  // zero pad rows (49..63) so garbage can't leak into Q/K/V
  for (int i = tid; i < 180; i += 512) {
    int row = 49 + i / 12, c8 = i % 12;
    uint4 z4 = {0u, 0u, 0u, 0u};
    *reinterpret_cast<uint4*>(&Xs[row][c8 * 8]) = z4;
  }
  // fused LN1 gather: 16 x 32-lane groups, 3 cols/lane, rows round-robin
  {
    int grp = tid >> 5, l32 = tid & 31;
    int c0 = l32 * 3;
    for (int row = grp; row < 49; row += 16) {
      const float* xr = xin + ((size_t)b * LROW + gidx[row]) * CD + c0;
      float a0 = xr[0], a1 = xr[1], a2 = xr[2];
      float s = a0 + a1 + a2;
#pragma unroll
      for (int off = 16; off >= 1; off >>= 1) s += __shfl_xor(s, off, 32);
      float mu = s * (1.f / 96.f);
      float d0 = a0 - mu, d1 = a1 - mu, d2 = a2 - mu;
      float q = d0 * d0 + d1 * d1 + d2 * d2;
#pragma unroll
      for (int off = 16; off >= 1; off >>= 1) q += __shfl_xor(q, off, 32);
      float rstd = rsqrtf(q * (1.f / 96.f) + 1e-6f);
      short* orow = &Xs[row][c0];
      orow[0] = f2bf(d0 * rstd * n1s[c0] + n1b[c0]);
      orow[1] = f2bf(d1 * rstd * n1s[c0 + 1] + n1b[c0 + 1]);
      orow[2] = f2bf(d2 * rstd * n1s[c0 + 2] + n1b[c0 + 2]);
    }
  }
  __syncthreads();

  // ---- qkv GEMM: M=64, N=288 (18 n-tiles over 8 waves), K=96 ----
  for (int nt = wid; nt < 18; nt += 8) {
    f32x4 acc[4];
#pragma unroll
    for (int mi = 0; mi < 4; ++mi) acc[mi] = (f32x4){0.f, 0.f, 0.f, 0.f};
#pragma unroll
    for (int kc = 0; kc < 3; ++kc) {
      bf8 bfr = *reinterpret_cast<const bf8*>(wwin + (size_t)(nt * 16 + lr) * 96 + kc * 32 + lg * 8);
#pragma unroll
      for (int mi = 0; mi < 4; ++mi) {
        bf8 afr = *reinterpret_cast<const bf8*>(&Xs[mi * 16 + lr][kc * 32 + lg * 8]);
        acc[mi] = __builtin_amdgcn_mfma_f32_16x16x32_bf16(afr, bfr, acc[mi], 0, 0, 0);
      }
    }
    int n = nt * 16 + lr;
    int sec = n / 96, within = n % 96;
    int hh = within >> 5, dd = within & 31;
    float bias = qkv_b[n];
#pragma unroll
    for (int mi = 0; mi < 4; ++mi)
#pragma unroll
      for (int r = 0; r < 4; ++r) {
        int mrow = mi * 16 + lg * 4 + r;
        float v = acc[mi][r] + bias;
        if (sec == 0)      Qs[hh][mrow][dd] = f2bf(v * (QSCALE * LOG2E));
        else if (sec == 1) Ks[hh][mrow][dd] = f2bf(v);
        else               Vt[hh][dd][mrow] = f2bf(v);
      }
  }
  __syncthreads();

  // ---- attention: 12 (head, q-tile) pairs over 8 waves; no-max softmax, tree sum ----
  int cntkv[16];
#pragma unroll
  for (int t = 0; t < 4; ++t)
#pragma unroll
    for (int r = 0; r < 4; ++r) cntkv[t * 4 + r] = cnt[t * 16 + lg * 4 + r];

  for (int p = wid; p < 12; p += 8) {
    int h = p >> 2, qt = p & 3;
    bf8 qf = *reinterpret_cast<const bf8*>(&Qs[h][qt * 16 + lr][lg * 8]);
    int cq = cnt[qt * 16 + lr];
    f32x4 z = {0.f, 0.f, 0.f, 0.f};
    f32x4 St[4];
    __builtin_amdgcn_s_setprio(1);
#pragma unroll
    for (int t = 0; t < 4; ++t) {
      bf8 kf = *reinterpret_cast<const bf8*>(&Ks[h][t * 16 + lr][lg * 8]);
      St[t] = __builtin_amdgcn_mfma_f32_16x16x32_bf16(kf, qf, z, 0, 0, 0);
    }
    __builtin_amdgcn_s_setprio(0);
    float pr[4];
#pragma unroll
    for (int t = 0; t < 4; ++t) {
      float p0 = fast_exp2(St[t][0] + ((cq == cntkv[t * 4 + 0]) ? 0.f : MASKLOG2));
      float p1 = fast_exp2(St[t][1] + ((cq == cntkv[t * 4 + 1]) ? 0.f : MASKLOG2));
      float p2 = fast_exp2(St[t][2] + ((cq == cntkv[t * 4 + 2]) ? 0.f : MASKLOG2));
      float p3 = fast_exp2(St[t][3] + ((cq == cntkv[t * 4 + 3]) ? 0.f : MASKLOG2));
      St[t][0] = p0; St[t][1] = p1; St[t][2] = p2; St[t][3] = p3;
      pr[t] = (p0 + p1) + (p2 + p3);
    }
    float rs = (pr[0] + pr[1]) + (pr[2] + pr[3]);
    rs += __shfl_xor(rs, 16);
    rs += __shfl_xor(rs, 32);
    float inv = 1.f / rs;
#pragma unroll
    for (int t = 0; t < 4; ++t) {
      uint2 w;
      w.x = pack_bf2(St[t][0], St[t][1]);
      w.y = pack_bf2(St[t][2], St[t][3]);
      *reinterpret_cast<uint2*>(&Ptw[wid][lr][t * 16 + lg * 4]) = w;
    }
    f32x4 O0 = {0.f, 0.f, 0.f, 0.f}, O1 = {0.f, 0.f, 0.f, 0.f};
    __builtin_amdgcn_s_setprio(1);
#pragma unroll
    for (int c = 0; c < 2; ++c) {
      bf8 pbf = *reinterpret_cast<const bf8*>(&Ptw[wid][lr][c * 32 + lg * 8]);
      bf8 v0 = *reinterpret_cast<const bf8*>(&Vt[h][lr][c * 32 + lg * 8]);
      bf8 v1 = *reinterpret_cast<const bf8*>(&Vt[h][16 + lr][c * 32 + lg * 8]);
      O0 = __builtin_amdgcn_mfma_f32_16x16x32_bf16(v0, pbf, O0, 0, 0, 0);
      O1 = __builtin_amdgcn_mfma_f32_16x16x32_bf16(v1, pbf, O1, 0, 0, 0);
    }
    __builtin_amdgcn_s_setprio(0);
#pragma unroll
    for (int r = 0; r < 4; ++r) {
      Os[qt * 16 + lr][h * 32 + lg * 4 + r] = f2bf(O0[r] * inv);
      Os[qt * 16 + lr][h * 32 + 16 + lg * 4 + r] = f2bf(O1[r] * inv);
    }
  }
  __syncthreads();

  // ---- proj GEMM (waves 0..3, full N per wave) + fused residual + LN-tb1 ----
  if (wid < 4) {
    int mt = wid;
    f32x4 acc[6];
#pragma unroll
    for (int nt = 0; nt < 6; ++nt) acc[nt] = (f32x4){0.f, 0.f, 0.f, 0.f};
#pragma unroll
    for (int kc = 0; kc < 3; ++kc) {
      bf8 afr = *reinterpret_cast<const bf8*>(&Os[mt * 16 + lr][kc * 32 + lg * 8]);
#pragma unroll
      for (int nt = 0; nt < 6; ++nt) {
        bf8 bfr = *reinterpret_cast<const bf8*>(wproj + (size_t)(nt * 16 + lr) * 96 + kc * 32 + lg * 8);
        acc[nt] = __builtin_amdgcn_mfma_f32_16x16x32_bf16(afr, bfr, acc[nt], 0, 0, 0);
      }
    }
    float pbv[6], gv[6], bv[6];
#pragma unroll
    for (int nt = 0; nt < 6; ++nt) {
      int col = nt * 16 + lr;
      pbv[nt] = proj_b[col];
      gv[nt] = ln1s[col];
      bv[nt] = ln1b[col];
    }
#pragma unroll
    for (int r = 0; r < 4; ++r) {
      int q = mt * 16 + lg * 4 + r;
      if (q >= 49) continue;           // uniform across the 16 lr lanes
      size_t rb = ((size_t)b * LROW + gidx[q]) * CD;
      float v[6];
#pragma unroll
      for (int nt = 0; nt < 6; ++nt)
        v[nt] = acc[nt][r] + pbv[nt] + xin[rb + nt * 16 + lr];
      float s = ((v[0] + v[1]) + (v[2] + v[3])) + (v[4] + v[5]);
      s += __shfl_xor(s, 1); s += __shfl_xor(s, 2);
      s += __shfl_xor(s, 4); s += __shfl_xor(s, 8);
      float mu = s * (1.f / 96.f);
      float d[6];
      float qs = 0.f;
#pragma unroll
      for (int nt = 0; nt < 6; ++nt) { d[nt] = v[nt] - mu; qs += d[nt] * d[nt]; }
      qs += __shfl_xor(qs, 1); qs += __shfl_xor(qs, 2);
      qs += __shfl_xor(qs, 4); qs += __shfl_xor(qs, 8);
      float rstd = rsqrtf(qs * (1.f / 96.f) + 1e-6f);
#pragma unroll
      for (int nt = 0; nt < 6; ++nt) {
        x1[rb + nt * 16 + lr] = v[nt];
        hb2[rb + nt * 16 + lr] = f2bf(d[nt] * rstd * gv[nt] + bv[nt]);
      }
    }
  }
}

// ---------------- qkv GEMM (bf16 MFMA); V stored tile-blocked [bh][49][32][64] ----------------
__global__ __launch_bounds__(256) void qkv_mfma_kernel(
    const short* __restrict__ A, const short* __restrict__ Bt,
    const float* __restrict__ bias,
    short* __restrict__ qb, short* __restrict__ kb, short* __restrict__ vtb) {
  __shared__ __align__(16) short As[2][128 * 32];
  __shared__ __align__(16) short Bs[2][64 * 32];
  int tid = threadIdx.x, lane = tid & 63, wid = tid >> 6;
  int lr = lane & 15, lg = lane >> 4;
  int m0 = blockIdx.x * 128, n0 = blockIdx.y * 64;
  const int K = 96;

  f32x4 acc[2][4];
#pragma unroll
  for (int i = 0; i < 2; ++i)
#pragma unroll
    for (int j = 0; j < 4; ++j) acc[i][j] = (f32x4){0.f, 0.f, 0.f, 0.f};

  auto stage = [&](int bf, int ks) {
    int k0 = ks * 32;
#pragma unroll
    for (int p = 0; p < 2; ++p) {
      int idx = tid + p * 256;
      GLOAD_LDS16(A + (size_t)(m0 + (idx >> 2)) * K + k0 + (idx & 3) * 8,
                  &As[bf][idx * 8]);
    }
    GLOAD_LDS16(Bt + (size_t)(n0 + (tid >> 2)) * K + k0 + (tid & 3) * 8,
                &Bs[bf][tid * 8]);
  };

  stage(0, 0);
  __syncthreads();
  int buf = 0;
  for (int ks = 0; ks < 3; ++ks) {
    if (ks + 1 < 3) stage(buf ^ 1, ks + 1);
    bf8 bfr[4], afr[2];
#pragma unroll
    for (int ni = 0; ni < 4; ++ni)
      bfr[ni] = *reinterpret_cast<const bf8*>(&Bs[buf][(ni * 16 + lr) * 32 + lg * 8]);
#pragma unroll
    for (int mi = 0; mi < 2; ++mi)
      afr[mi] = *reinterpret_cast<const bf8*>(&As[buf][(wid * 32 + mi * 16 + lr) * 32 + lg * 8]);
    __builtin_amdgcn_s_setprio(1);
#pragma unroll
    for (int mi = 0; mi < 2; ++mi)
#pragma unroll
      for (int ni = 0; ni < 4; ++ni)
        acc[mi][ni] = __builtin_amdgcn_mfma_f32_16x16x32_bf16(afr[mi], bfr[ni], acc[mi][ni], 0, 0, 0);
    __builtin_amdgcn_s_setprio(0);
    __syncthreads();
    buf ^= 1;
  }

#pragma unroll
  for (int mi = 0; mi < 2; ++mi)
#pragma unroll
    for (int ni = 0; ni < 4; ++ni)
#pragma unroll
      for (int r = 0; r < 4; ++r) {
        int mrow = m0 + wid * 32 + mi * 16 + lg * 4 + r;
        int n = n0 + ni * 16 + lr;
        if (n < 288) {
          float v = acc[mi][ni][r] + bias[n];
          int sec = n / 96, within = n % 96;
          int hh = within >> 5, dd = within & 31;
          int bb = mrow / LROW, nn = mrow - bb * LROW;
          size_t bh = (size_t)bb * 3 + hh;
          if (sec == 0)      qb[(bh * LROW + nn) * 32 + dd] = f2bf(v * (QSCALE * LOG2E));
          else if (sec == 1) kb[(bh * LROW + nn) * 32 + dd] = f2bf(v);
          else               vtb[((bh * 49 + (nn >> 6)) * 32 + dd) * 64 + (nn & 63)] = f2bf(v);
        }
      }
}

// ---------------- flash attention v10: XCD-swizzled block mapping, tile-blocked V, ones-MFMA l ----------------
// grid 3528 flat blocks; swizzle gives each XCD 441 contiguous work items = ~9 (bh,split) groups,
// so each (bh,split)'s shared K/V slice (~134KB) stays resident in ONE XCD's L2.
__global__ __launch_bounds__(128) void flash_mfma_kernel(
    const short* __restrict__ qb, const short* __restrict__ kb,
    const short* __restrict__ vtb,
    short* __restrict__ pOb, float* __restrict__ pl) {
  __shared__ __align__(16) short Pt[2][2][16][72];  // [wave][g][q][kv]; 144B rows (no aliasing)
  int tid = threadIdx.x, lane = tid & 63, wid = tid >> 6;
  int lr = lane & 15, lg = lane >> 4;

  // XCD-aware bijective swizzle: 3528 = 8 * 441
  int flat = blockIdx.x;
  int swz = (flat & 7) * 441 + (flat >> 3);
  int qt = swz % 49;
  int yz = swz / 49;
  int bh = yz % 12, s = yz / 12;

  int q0 = qt * 64 + wid * 32;
  const short* qbb = qb + (size_t)bh * LROW * 32;
  const short* kbase = kb + (size_t)bh * LROW * 32 + lr * 32 + lg * 8;
  const short* vbase = vtb + (size_t)bh * 49 * 2048 + lr * 64 + lg * 8;  // tile t at +t*2048

  bf8 qf0 = *reinterpret_cast<const bf8*>(qbb + (size_t)(q0 + lr) * 32 + lg * 8);
  bf8 qf1 = *reinterpret_cast<const bf8*>(qbb + (size_t)(q0 + 16 + lr) * 32 + lg * 8);

  const bf8 onesf = {16256, 16256, 16256, 16256, 16256, 16256, 16256, 16256};  // bf16 1.0

  f32x4 O00 = {0.f,0.f,0.f,0.f}, O01 = {0.f,0.f,0.f,0.f};
  f32x4 O10 = {0.f,0.f,0.f,0.f}, O11 = {0.f,0.f,0.f,0.f};
  f32x4 La0 = {0.f,0.f,0.f,0.f}, La1 = {0.f,0.f,0.f,0.f};  // l accumulators (all rows equal)

  const int tbl[7] = {0, 9, 17, 25, 33, 41, 49};
  int t0 = tbl[s], t1 = tbl[s + 1];

  bf8 kA[4], vA[4], kB[4], vB[4];

  auto loadt = [&](bf8 (&Kf)[4], bf8 (&Vf)[4], int kt) {
    const short* kp = kbase + (size_t)kt * 2048;
#pragma unroll
    for (int t = 0; t < 4; ++t) Kf[t] = *reinterpret_cast<const bf8*>(kp + t * 512);
    const short* vp = vbase + (size_t)kt * 2048;   // rows d=lr; +1024 => d=16+lr
#pragma unroll
    for (int c = 0; c < 2; ++c) {
      Vf[c]     = *reinterpret_cast<const bf8*>(vp + c * 32);
      Vf[2 + c] = *reinterpret_cast<const bf8*>(vp + 1024 + c * 32);
    }
  };

  auto body = [&](bf8 (&Kf)[4], bf8 (&Vf)[4]) {
    f32x4 z = {0.f, 0.f, 0.f, 0.f};
#pragma unroll
    for (int g = 0; g < 2; ++g) {
      bf8 qf = g ? qf1 : qf0;
      f32x4 St[4];
      __builtin_amdgcn_s_setprio(1);
#pragma unroll
      for (int t = 0; t < 4; ++t)
        St[t] = __builtin_amdgcn_mfma_f32_16x16x32_bf16(Kf[t], qf, z, 0, 0, 0);
      __builtin_amdgcn_s_setprio(0);
#pragma unroll
      for (int t = 0; t < 4; ++t) {
        float p0 = fast_exp2(St[t][0]);
        float p1 = fast_exp2(St[t][1]);
        float p2 = fast_exp2(St[t][2]);
        float p3 = fast_exp2(St[t][3]);
        uint2 w;
        w.x = pack_bf2(p0, p1);
        w.y = pack_bf2(p2, p3);
        *reinterpret_cast<uint2*>(&Pt[wid][g][lr][t * 16 + lg * 4]) = w;
      }
    }
    __builtin_amdgcn_s_setprio(1);
#pragma unroll
    for (int g = 0; g < 2; ++g) {
      f32x4& Oh0 = g ? O10 : O00;
      f32x4& Oh1 = g ? O11 : O01;
      f32x4& La  = g ? La1 : La0;
#pragma unroll
      for (int c = 0; c < 2; ++c) {
        bf8 pbf = *reinterpret_cast<const bf8*>(&Pt[wid][g][lr][c * 32 + lg * 8]);
        Oh0 = __builtin_amdgcn_mfma_f32_16x16x32_bf16(Vf[c], pbf, Oh0, 0, 0, 0);
        Oh1 = __builtin_amdgcn_mfma_f32_16x16x32_bf16(Vf[2 + c], pbf, Oh1, 0, 0, 0);
        La  = __builtin_amdgcn_mfma_f32_16x16x32_bf16(onesf, pbf, La, 0, 0, 0);
      }
    }
    __builtin_amdgcn_s_setprio(0);
  };

  loadt(kA, vA, t0);
  int kt = t0;
  for (; kt + 2 <= t1 - 1; kt += 2) {
    loadt(kB, vB, kt + 1);
    body(kA, vA);
    loadt(kA, vA, kt + 2);
    body(kB, vB);
  }
  if (kt < t1 - 1) {
    loadt(kB, vB, kt + 1);
    body(kA, vA);
    body(kB, vB);
  } else {
    body(kA, vA);
  }

  // bf16 unnormalized partials; lane (lr,lg) holds d = lg*4+r (+16) for q = q0(+16)+lr
  size_t rbase = (size_t)(s * 12 + bh) * LROW;
  size_t r0 = (rbase + q0 + lr) * 32;
  size_t r1 = (rbase + q0 + 16 + lr) * 32;
  uint2 w;
  w.x = pack_bf2r(O00[0], O00[1]); w.y = pack_bf2r(O00[2], O00[3]);
  *reinterpret_cast<uint2*>(&pOb[r0 + lg * 4]) = w;
  w.x = pack_bf2r(O01[0], O01[1]); w.y = pack_bf2r(O01[2], O01[3]);
  *reinterpret_cast<uint2*>(&pOb[r0 + 16 + lg * 4]) = w;
  w.x = pack_bf2r(O10[0], O10[1]); w.y = pack_bf2r(O10[2], O10[3]);
  *reinterpret_cast<uint2*>(&pOb[r1 + lg * 4]) = w;
  w.x = pack_bf2r(O11[0], O11[1]); w.y = pack_bf2r(O11[2], O11[3]);
  *reinterpret_cast<uint2*>(&pOb[r1 + 16 + lg * 4]) = w;
  if (lg == 0) {
    pl[rbase + q0 + lr] = La0[0];
    pl[rbase + q0 + 16 + lr] = La1[0];
  }
}

// ---------------- out-proj GEMM with fused 6-split merge (A-stage) + residual + LN2 ----------------
__global__ __launch_bounds__(256) void gemm_out_merge_ln_kernel(
    const short* __restrict__ pOb, const float* __restrict__ pl,
    const short* __restrict__ Bt,
    const float* __restrict__ bias, const float* __restrict__ res,
    const float* __restrict__ g2, const float* __restrict__ b2,
    float* __restrict__ x2, short* __restrict__ hb3) {
  __shared__ __align__(16) short As[128][104];   // merged bf16 A, padded rows
  __shared__ __align__(16) short Bs[2][96 * 32];
  int tid = threadIdx.x, lane = tid & 63, wid = tid >> 6;
  int lr = lane & 15, lg = lane >> 4;
  int m0 = blockIdx.x * 128;
  const int K = 96;
  const int NR = 12 * LROW;

  // ---- merge-stage A: thread handles (row, head) pairs ----
  for (int pi = tid; pi < 384; pi += 256) {
    int rloc = pi / 3, h = pi % 3;
    int grow = m0 + rloc;
    int bb = grow / LROW, q = grow - bb * LROW;
    size_t pbase = ((size_t)(bb * 3 + h)) * LROW + q;
    float l = 0.f;
#pragma unroll
    for (int s = 0; s < 6; ++s) l += pl[(size_t)s * NR + pbase];
    float invl = 1.f / l;
    float o[32];
#pragma unroll
    for (int d = 0; d < 32; ++d) o[d] = 0.f;
#pragma unroll
    for (int s = 0; s < 6; ++s) {
      const uint4* p4 = reinterpret_cast<const uint4*>(pOb + ((size_t)s * NR + pbase) * 32);
#pragma unroll
      for (int u = 0; u < 4; ++u) {
        uint4 v = p4[u];
        unsigned wd0 = v.x, wd1 = v.y, wd2 = v.z, wd3 = v.w;
        o[u*8+0] += __uint_as_float(wd0 << 16);
        o[u*8+1] += __uint_as_float(wd0 & 0xffff0000u);
        o[u*8+2] += __uint_as_float(wd1 << 16);
        o[u*8+3] += __uint_as_float(wd1 & 0xffff0000u);
        o[u*8+4] += __uint_as_float(wd2 << 16);
        o[u*8+5] += __uint_as_float(wd2 & 0xffff0000u);
        o[u*8+6] += __uint_as_float(wd3 << 16);
        o[u*8+7] += __uint_as_float(wd3 & 0xffff0000u);
      }
    }
    short* dst = &As[rloc][h * 32];
#pragma unroll
    for (int u2 = 0; u2 < 4; ++u2) {
      uint4 w;
      w.x = pack_bf2r(o[u2*8+0]*invl, o[u2*8+1]*invl);
      w.y = pack_bf2r(o[u2*8+2]*invl, o[u2*8+3]*invl);
      w.z = pack_bf2r(o[u2*8+4]*invl, o[u2*8+5]*invl);
      w.w = pack_bf2r(o[u2*8+6]*invl, o[u2*8+7]*invl);
      *reinterpret_cast<uint4*>(dst + u2 * 8) = w;
    }
  }

  f32x4 acc[2][6];
#pragma unroll
  for (int i = 0; i < 2; ++i)
#pragma unroll
    for (int j = 0; j < 6; ++j) acc[i][j] = (f32x4){0.f, 0.f, 0.f, 0.f};

  auto stageB = [&](int bf, int ks) {
    int k0 = ks * 32;
    for (int l = tid; l < 384; l += 256) {
      GLOAD_LDS16(Bt + (size_t)(l >> 2) * K + k0 + (l & 3) * 8,
                  &Bs[bf][l * 8]);
    }
  };

  stageB(0, 0);
  __syncthreads();   // drains merge ds_writes + GLOAD vmcnt
  int buf = 0;
  for (int ks = 0; ks < 3; ++ks) {
    if (ks + 1 < 3) stageB(buf ^ 1, ks + 1);
    bf8 bfr[6], afr[2];
#pragma unroll
    for (int ni = 0; ni < 6; ++ni)
      bfr[ni] = *reinterpret_cast<const bf8*>(&Bs[buf][(ni * 16 + lr) * 32 + lg * 8]);
#pragma unroll
    for (int mi = 0; mi < 2; ++mi)
      afr[mi] = *reinterpret_cast<const bf8*>(&As[wid * 32 + mi * 16 + lr][ks * 32 + lg * 8]);
    __builtin_amdgcn_s_setprio(1);
#pragma unroll
    for (int mi = 0; mi < 2; ++mi)
#pragma unroll
      for (int ni = 0; ni < 6; ++ni)
        acc[mi][ni] = __builtin_amdgcn_mfma_f32_16x16x32_bf16(afr[mi], bfr[ni], acc[mi][ni], 0, 0, 0);
    __builtin_amdgcn_s_setprio(0);
    __syncthreads();
    buf ^= 1;
  }

  float bb[6], gv[6], bv[6];
#pragma unroll
  for (int ni = 0; ni < 6; ++ni) {
    int col = ni * 16 + lr;
    bb[ni] = bias[col];
    gv[ni] = g2[col];
    bv[ni] = b2[col];
  }
#pragma unroll
  for (int mi = 0; mi < 2; ++mi)
#pragma unroll
    for (int r = 0; r < 4; ++r) {
      int row = m0 + wid * 32 + mi * 16 + lg * 4 + r;
      size_t rb = (size_t)row * CD;
      float v[6];
#pragma unroll
      for (int ni = 0; ni < 6; ++ni)
        v[ni] = acc[mi][ni][r] + bb[ni] + res[rb + ni * 16 + lr];
      float s = ((v[0] + v[1]) + (v[2] + v[3])) + (v[4] + v[5]);
      s += __shfl_xor(s, 1); s += __shfl_xor(s, 2);
      s += __shfl_xor(s, 4); s += __shfl_xor(s, 8);
      float mu = s * (1.f / 96.f);
      float d[6];
      float qs = 0.f;
#pragma unroll
      for (int ni = 0; ni < 6; ++ni) { d[ni] = v[ni] - mu; qs += d[ni] * d[ni]; }
      qs += __shfl_xor(qs, 1); qs += __shfl_xor(qs, 2);
      qs += __shfl_xor(qs, 4); qs += __shfl_xor(qs, 8);
      float rstd = rsqrtf(qs * (1.f / 96.f) + 1e-6f);
#pragma unroll
      for (int ni = 0; ni < 6; ++ni) {
        x2[rb + ni * 16 + lr] = v[ni];
        hb3[rb + ni * 16 + lr] = f2bf(d[ni] * rstd * gv[ni] + bv[ni]);
      }
    }
}

// ---------------- fused MLP: fc1 (gelu) -> LDS -> fc2 (+bias+residual) -> out ----------------
__global__ __launch_bounds__(256) void mlp_kernel(
    const short* __restrict__ hb3, const short* __restrict__ wfc1,
    const float* __restrict__ fc1_b, const short* __restrict__ wfc2,
    const float* __restrict__ fc2_b, const float* __restrict__ resid,
    float* __restrict__ outx) {
  __shared__ __align__(16) short Ah[64][104];
  __shared__ __align__(16) short T[64][392];
  int tid = threadIdx.x, lane = tid & 63, wid = tid >> 6;
  int lr = lane & 15, lg = lane >> 4;
  int m0 = blockIdx.x * 64;

  for (int i = tid; i < 768; i += 256) {
    int row = i / 12, c8 = i % 12;
    uint4 v = *reinterpret_cast<const uint4*>(hb3 + (size_t)(m0 + row) * 96 + c8 * 8);
    *reinterpret_cast<uint4*>(&Ah[row][c8 * 8]) = v;
  }
  __syncthreads();

  // ---- fc1: M=64, N-strip=96 per wave, K=96 ----
  {
    f32x4 acc[4][6];
#pragma unroll
    for (int i = 0; i < 4; ++i)
#pragma unroll
      for (int j = 0; j < 6; ++j) acc[i][j] = (f32x4){0.f, 0.f, 0.f, 0.f};
#pragma unroll
    for (int kc = 0; kc < 3; ++kc) {
      bf8 bfr[6], afr[4];
#pragma unroll
      for (int nt = 0; nt < 6; ++nt)
        bfr[nt] = *reinterpret_cast<const bf8*>(wfc1 + (size_t)(wid * 96 + nt * 16 + lr) * 96 + kc * 32 + lg * 8);
#pragma unroll
      for (int mi = 0; mi < 4; ++mi)
        afr[mi] = *reinterpret_cast<const bf8*>(&Ah[mi * 16 + lr][kc * 32 + lg * 8]);
      __builtin_amdgcn_s_setprio(1);
#pragma unroll
      for (int mi = 0; mi < 4; ++mi)
#pragma unroll
        for (int nt = 0; nt < 6; ++nt)
          acc[mi][nt] = __builtin_amdgcn_mfma_f32_16x16x32_bf16(afr[mi], bfr[nt], acc[mi][nt], 0, 0, 0);
      __builtin_amdgcn_s_setprio(0);
    }
#pragma unroll
    for (int nt = 0; nt < 6; ++nt) {
      float b1 = fc1_b[wid * 96 + nt * 16 + lr];
      int col = wid * 96 + nt * 16 + lr;
#pragma unroll
      for (int mi = 0; mi < 4; ++mi)
#pragma unroll
        for (int r = 0; r < 4; ++r)
          T[mi * 16 + lg * 4 + r][col] = f2bf(gelu_f(acc[mi][nt][r] + b1));
    }
  }
  __syncthreads();

  // ---- fc2: rows [w*16,(w+1)*16), N=96, K=384 ----
  {
    f32x4 a2[6];
#pragma unroll
    for (int j = 0; j < 6; ++j) a2[j] = (f32x4){0.f, 0.f, 0.f, 0.f};
#pragma unroll
    for (int kc = 0; kc < 12; ++kc) {
      bf8 afr2 = *reinterpret_cast<const bf8*>(&T[wid * 16 + lr][kc * 32 + lg * 8]);
      bf8 bfr2[6];
#pragma unroll
      for (int nt = 0; nt < 6; ++nt)
        bfr2[nt] = *reinterpret_cast<const bf8*>(wfc2 + (size_t)(nt * 16 + lr) * 384 + kc * 32 + lg * 8);
      __builtin_amdgcn_s_setprio(1);
#pragma unroll
      for (int nt = 0; nt < 6; ++nt)
        a2[nt] = __builtin_amdgcn_mfma_f32_16x16x32_bf16(afr2, bfr2[nt], a2[nt], 0, 0, 0);
      __builtin_amdgcn_s_setprio(0);
    }
#pragma unroll
    for (int nt = 0; nt < 6; ++nt) {
      float b2v = fc2_b[nt * 16 + lr];
#pragma unroll
      for (int r = 0; r < 4; ++r) {
        int row = m0 + wid * 16 + lg * 4 + r;
        size_t idx = (size_t)row * CD + nt * 16 + lr;
        outx[idx] = a2[nt][r] + b2v + resid[idx];
      }
    }
  }
}

extern "C" void kernel_launch(void* const* d_in, const int* in_sizes, int n_in,
                              void* d_out, int out_size, void* d_ws, size_t ws_size,
                              hipStream_t stream) {
  const float* x      = (const float*)d_in[0];
  const int*   Hp     = (const int*)d_in[1];
  const int*   Wp     = (const int*)d_in[2];
  const float* n1s    = (const float*)d_in[3];
  const float* n1b    = (const float*)d_in[4];
  const float* qkv_w  = (const float*)d_in[5];
  const float* qkv_b  = (const float*)d_in[6];
  const float* proj_w = (const float*)d_in[7];
  const float* proj_b = (const float*)d_in[8];
  const float* ln1s   = (const float*)d_in[9];
  const float* ln1b   = (const float*)d_in[10];
  const float* qkv2_w = (const float*)d_in[11];
  const float* qkv2_b = (const float*)d_in[12];
  const float* out_w  = (const float*)d_in[13];
  const float* out_b  = (const float*)d_in[14];
  const float* ln2s   = (const float*)d_in[15];
  const float* ln2b   = (const float*)d_in[16];
  const float* fc1_w  = (const float*)d_in[17];
  const float* fc1_b  = (const float*)d_in[18];
  const float* fc2_w  = (const float*)d_in[19];
  const float* fc2_b  = (const float*)d_in[20];

  float* wsf = (float*)d_ws;
  const size_t U = (size_t)4 * LROW * CD;  // 1,204,224
  float* x1   = wsf;                           // [0,U) fp32 residual (win out)
  short* qb   = (short*)(wsf + 4 * U + U / 2); // [4.5U,5U)
  short* kb   = qb + U;                        // [5U,5.5U)
  short* vtb  = kb + U;                        // [5.5U,6U); 12*49*2048 shorts (tile-blocked)
  short* wall = (short*)(wsf + 6 * U);         // contiguous bf16 weights, 165888 shorts
  short* wqkv = wall;                          // 320*96
  short* wout = wqkv + 320 * 96;               // 128*96
  short* wfc1 = wout + 128 * 96;               // 384*96
  short* wfc2 = wfc1 + 384 * 96;               // 128*384
  short* wwin = wfc2 + 128 * 384;              // 288*96
  short* wproj = wwin + 288 * 96;              // 96*96
  short* hb2  = (short*)(wsf + 6 * U + 82944); // bf16 LN-tb1 out (U shorts)
  // flash partials overlay [U,4U): pOb bf16 6 splits (3U floats); pl at [4U,4.2U)
  short* pOb  = (short*)(wsf + U);             // 6 * 12*LROW*32 shorts = 3U floats
  float* pl   = wsf + 4 * U;                   // 6 * 12*LROW floats
  // post-flash outputs live OUTSIDE the pOb overlay (qb/kb/vtb dead after flash):
  float* x2f  = (float*)qb;                    // U floats over [4.5U,5.5U)
  short* hb3  = vtb;                           // U shorts, LN2 out bf16
  float* outx = (float*)d_out;

  const int M = 4 * LROW;  // 12544

  cvt_all_kernel<<<(165888 + 255) / 256, 256, 0, stream>>>(
      qkv2_w, out_w, fc1_w, fc2_w, qkv_w, proj_w, wall, Hp, Wp, outx + U);

  win_attn_kernel<<<256, 512, 0, stream>>>(x, n1s, n1b, wwin, qkv_b, wproj, proj_b,
                                           ln1s, ln1b, x1, hb2);
  qkv_mfma_kernel<<<dim3(M / 128, 5), 256, 0, stream>>>(hb2, wqkv, qkv2_b, qb, kb, vtb);
  flash_mfma_kernel<<<3528, 128, 0, stream>>>(qb, kb, vtb, pOb, pl);
  gemm_out_merge_ln_kernel<<<M / 128, 256, 0, stream>>>(pOb, pl, wout, out_b, x1,
                                                        ln2s, ln2b, x2f, hb3);
  mlp_kernel<<<M / 64, 256, 0, stream>>>(hb3, wfc1, fc1_b, wfc2, fc2_b, x2f, outx);
}

// Round 17
// 113.816 us; speedup vs baseline: 1.0382x; 1.0382x over previous
//
#include <hip/hip_runtime.h>
#include <hip/hip_bf16.h>

#define CD 96
#define LROW 3136          // 56*56
#define QSCALE 0.17677669529663687f  // 1/sqrt(32)
#define LOG2E 1.4426950408889634f
#define MASKLOG2 -144.26950408889634f // -100 * log2(e)

using f32x4 = __attribute__((ext_vector_type(4))) float;
using bf8   = __attribute__((ext_vector_type(8))) short;

__device__ __forceinline__ short f2bf(float f) {
  union { float f; unsigned u; } v; v.f = f;
  unsigned r = v.u + 0x7fffu + ((v.u >> 16) & 1u);
  return (short)(r >> 16);
}
__device__ __forceinline__ float bf2f(unsigned short s) {
  return __uint_as_float((unsigned)s << 16);
}
__device__ __forceinline__ unsigned pack_bf2(float lo, float hi) {
  return (__float_as_uint(hi) & 0xffff0000u) | (__float_as_uint(lo) >> 16);
}
__device__ __forceinline__ unsigned pack_bf2r(float lo, float hi) {
  return ((unsigned)(unsigned short)f2bf(hi) << 16) | (unsigned short)f2bf(lo);
}
__device__ __forceinline__ float fast_exp2(float x) {
  return __builtin_amdgcn_exp2f(x);
}
// gelu tanh-approx via exp2: 0.5v(1+tanh(u)) = v*e/(e+1), e = exp(2u)
__device__ __forceinline__ float gelu_f(float v) {
  float u = 0.7978845608028654f * (v + 0.044715f * v * v * v);
  float e = fast_exp2(u * 2.8853900817779268f);  // 2*log2(e)
  return v * e * __builtin_amdgcn_rcpf(e + 1.f);
}

#define GLOAD_LDS16(src, dst) \
  __builtin_amdgcn_global_load_lds((const __attribute__((address_space(1))) void*)(src), \
                                   (__attribute__((address_space(3))) void*)(dst), 16, 0, 0)

// ---------------- LayerNorm (LN1 only): 32-lane groups, 3 cols/lane -> bf16 ----------------
__global__ __launch_bounds__(256) void ln_kernel(const float* __restrict__ x,
                                                 const float* __restrict__ g,
                                                 const float* __restrict__ b,
                                                 short* __restrict__ out, int rows) {
  int slot = threadIdx.x >> 5, l32 = threadIdx.x & 31;
  int row = blockIdx.x * 8 + slot;
  if (row >= rows) return;
  const float* xr = x + (size_t)row * CD + l32 * 3;
  float a0 = xr[0], a1 = xr[1], a2 = xr[2];
  float s = a0 + a1 + a2;
#pragma unroll
  for (int off = 16; off >= 1; off >>= 1) s += __shfl_xor(s, off, 32);
  float mu = s * (1.f / 96.f);
  float d0 = a0 - mu, d1 = a1 - mu, d2 = a2 - mu;
  float q = d0 * d0 + d1 * d1 + d2 * d2;
#pragma unroll
  for (int off = 16; off >= 1; off >>= 1) q += __shfl_xor(q, off, 32);
  float rstd = rsqrtf(q * (1.f / 96.f) + 1e-6f);
  int c0 = l32 * 3;
  short* orow = out + (size_t)row * CD + c0;
  orow[0] = f2bf(d0 * rstd * g[c0] + b[c0]);
  orow[1] = f2bf(d1 * rstd * g[c0 + 1] + b[c0 + 1]);
  orow[2] = f2bf(d2 * rstd * g[c0 + 2] + b[c0 + 2]);
}

// ---------------- fused weight convert (+ tail scalars) ----------------
__global__ __launch_bounds__(256) void cvt_all_kernel(
    const float* __restrict__ qkv2_w, const float* __restrict__ out_w,
    const float* __restrict__ fc1_w, const float* __restrict__ fc2_w,
    const float* __restrict__ qkv_w, const float* __restrict__ proj_w,
    short* __restrict__ dst,
    const int* __restrict__ Hp, const int* __restrict__ Wp,
    float* __restrict__ tail_out) {
  int idx = blockIdx.x * 256 + threadIdx.x;
  if (idx == 0) {
    tail_out[0] = (float)Hp[0];
    tail_out[1] = (float)Wp[0];
  }
  if (idx >= 165888) return;
  const float* W; int K, N, off;
  if (idx < 30720)       { W = qkv2_w; K = 96;  N = 288; off = idx; }
  else if (idx < 43008)  { W = out_w;  K = 96;  N = 96;  off = idx - 30720; }
  else if (idx < 79872)  { W = fc1_w;  K = 96;  N = 384; off = idx - 43008; }
  else if (idx < 129024) { W = fc2_w;  K = 384; N = 96;  off = idx - 79872; }
  else if (idx < 156672) { W = qkv_w;  K = 96;  N = 288; off = idx - 129024; }
  else                   { W = proj_w; K = 96;  N = 96;  off = idx - 156672; }
  int nr = off / K, kk = off - nr * K;
  float v = (nr < N) ? W[(size_t)kk * N + nr] : 0.f;
  dst[idx] = f2bf(v);
}

// ---------------- MFMA shifted-window attention + fused LN-tb1 epilogue ----------------
__global__ __launch_bounds__(512) void win_attn_kernel(
    const short* __restrict__ hb_in, const float* __restrict__ xin,
    const short* __restrict__ wwin, const float* __restrict__ qkv_b,
    const short* __restrict__ wproj, const float* __restrict__ proj_b,
    const float* __restrict__ ln1s, const float* __restrict__ ln1b,
    float* __restrict__ x1, short* __restrict__ hb2) {
  __shared__ __align__(16) short Xs[64][104];
  __shared__ __align__(16) short Qs[3][64][40];
  __shared__ __align__(16) short Ks[3][64][40];
  __shared__ __align__(16) short Vt[3][32][72];
  __shared__ __align__(16) short Os[64][104];
  __shared__ __align__(16) short Ptw[8][16][72];
  __shared__ int cnt[64];
  __shared__ int gidx[49];

  int tid = threadIdx.x, lane = tid & 63, wid = tid >> 6;
  int lr = lane & 15, lg = lane >> 4;
  int b = blockIdx.x >> 6, w64 = blockIdx.x & 63;
  int wr = w64 >> 3, wc = w64 & 7;

  if (tid < 64) {
    if (tid < 49) {
      int i = tid / 7, j = tid % 7;
      int sh = wr * 7 + i, sw = wc * 7 + j;
      int hr = (sh < 49) ? 0 : ((sh < 53) ? 1 : 2);
      int wreg = (sw < 49) ? 0 : ((sw < 53) ? 1 : 2);
      cnt[tid] = hr * 3 + wreg;
      gidx[tid] = ((sh + 3) % 56) * 56 + ((sw + 3) % 56);
    } else {
      cnt[tid] = -1;
    }
  }
  __syncthreads();

  for (int c = tid; c < 768; c += 512) {
    int row = c / 12, cc = c % 12;
    uint4 v = {0u, 0u, 0u, 0u};
    if (row < 49) v = *reinterpret_cast<const uint4*>(hb_in + ((size_t)b * LROW + gidx[row]) * 96 + cc * 8);
    *reinterpret_cast<uint4*>(&Xs[row][cc * 8]) = v;
  }
  __syncthreads();

  // ---- qkv GEMM: M=64, N=288 (18 n-tiles over 8 waves), K=96 ----
  for (int nt = wid; nt < 18; nt += 8) {
    f32x4 acc[4];
#pragma unroll
    for (int mi = 0; mi < 4; ++mi) acc[mi] = (f32x4){0.f, 0.f, 0.f, 0.f};
#pragma unroll
    for (int kc = 0; kc < 3; ++kc) {
      bf8 bfr = *reinterpret_cast<const bf8*>(wwin + (size_t)(nt * 16 + lr) * 96 + kc * 32 + lg * 8);
#pragma unroll
      for (int mi = 0; mi < 4; ++mi) {
        bf8 afr = *reinterpret_cast<const bf8*>(&Xs[mi * 16 + lr][kc * 32 + lg * 8]);
        acc[mi] = __builtin_amdgcn_mfma_f32_16x16x32_bf16(afr, bfr, acc[mi], 0, 0, 0);
      }
    }
    int n = nt * 16 + lr;
    int sec = n / 96, within = n % 96;
    int hh = within >> 5, dd = within & 31;
    float bias = qkv_b[n];
#pragma unroll
    for (int mi = 0; mi < 4; ++mi)
#pragma unroll
      for (int r = 0; r < 4; ++r) {
        int mrow = mi * 16 + lg * 4 + r;
        float v = acc[mi][r] + bias;
        if (sec == 0)      Qs[hh][mrow][dd] = f2bf(v * (QSCALE * LOG2E));
        else if (sec == 1) Ks[hh][mrow][dd] = f2bf(v);
        else               Vt[hh][dd][mrow] = f2bf(v);
      }
  }
  __syncthreads();

  // ---- attention: 12 (head, q-tile) pairs over 8 waves; no-max softmax, tree sum ----
  int cntkv[16];
#pragma unroll
  for (int t = 0; t < 4; ++t)
#pragma unroll
    for (int r = 0; r < 4; ++r) cntkv[t * 4 + r] = cnt[t * 16 + lg * 4 + r];

  for (int p = wid; p < 12; p += 8) {
    int h = p >> 2, qt = p & 3;
    bf8 qf = *reinterpret_cast<const bf8*>(&Qs[h][qt * 16 + lr][lg * 8]);
    int cq = cnt[qt * 16 + lr];
    f32x4 z = {0.f, 0.f, 0.f, 0.f};
    f32x4 St[4];
    __builtin_amdgcn_s_setprio(1);
#pragma unroll
    for (int t = 0; t < 4; ++t) {
      bf8 kf = *reinterpret_cast<const bf8*>(&Ks[h][t * 16 + lr][lg * 8]);
      St[t] = __builtin_amdgcn_mfma_f32_16x16x32_bf16(kf, qf, z, 0, 0, 0);
    }
    __builtin_amdgcn_s_setprio(0);
    float pr[4];
#pragma unroll
    for (int t = 0; t < 4; ++t) {
      float p0 = fast_exp2(St[t][0] + ((cq == cntkv[t * 4 + 0]) ? 0.f : MASKLOG2));
      float p1 = fast_exp2(St[t][1] + ((cq == cntkv[t * 4 + 1]) ? 0.f : MASKLOG2));
      float p2 = fast_exp2(St[t][2] + ((cq == cntkv[t * 4 + 2]) ? 0.f : MASKLOG2));
      float p3 = fast_exp2(St[t][3] + ((cq == cntkv[t * 4 + 3]) ? 0.f : MASKLOG2));
      St[t][0] = p0; St[t][1] = p1; St[t][2] = p2; St[t][3] = p3;
      pr[t] = (p0 + p1) + (p2 + p3);
    }
    float rs = (pr[0] + pr[1]) + (pr[2] + pr[3]);
    rs += __shfl_xor(rs, 16);
    rs += __shfl_xor(rs, 32);
    float inv = 1.f / rs;
#pragma unroll
    for (int t = 0; t < 4; ++t) {
      uint2 w;
      w.x = pack_bf2(St[t][0], St[t][1]);
      w.y = pack_bf2(St[t][2], St[t][3]);
      *reinterpret_cast<uint2*>(&Ptw[wid][lr][t * 16 + lg * 4]) = w;
    }
    f32x4 O0 = {0.f, 0.f, 0.f, 0.f}, O1 = {0.f, 0.f, 0.f, 0.f};
    __builtin_amdgcn_s_setprio(1);
#pragma unroll
    for (int c = 0; c < 2; ++c) {
      bf8 pbf = *reinterpret_cast<const bf8*>(&Ptw[wid][lr][c * 32 + lg * 8]);
      bf8 v0 = *reinterpret_cast<const bf8*>(&Vt[h][lr][c * 32 + lg * 8]);
      bf8 v1 = *reinterpret_cast<const bf8*>(&Vt[h][16 + lr][c * 32 + lg * 8]);
      O0 = __builtin_amdgcn_mfma_f32_16x16x32_bf16(v0, pbf, O0, 0, 0, 0);
      O1 = __builtin_amdgcn_mfma_f32_16x16x32_bf16(v1, pbf, O1, 0, 0, 0);
    }
    __builtin_amdgcn_s_setprio(0);
#pragma unroll
    for (int r = 0; r < 4; ++r) {
      Os[qt * 16 + lr][h * 32 + lg * 4 + r] = f2bf(O0[r] * inv);
      Os[qt * 16 + lr][h * 32 + 16 + lg * 4 + r] = f2bf(O1[r] * inv);
    }
  }
  __syncthreads();

  // ---- proj GEMM (waves 0..3, full N per wave) + fused residual + LN-tb1 ----
  if (wid < 4) {
    int mt = wid;
    f32x4 acc[6];
#pragma unroll
    for (int nt = 0; nt < 6; ++nt) acc[nt] = (f32x4){0.f, 0.f, 0.f, 0.f};
#pragma unroll
    for (int kc = 0; kc < 3; ++kc) {
      bf8 afr = *reinterpret_cast<const bf8*>(&Os[mt * 16 + lr][kc * 32 + lg * 8]);
#pragma unroll
      for (int nt = 0; nt < 6; ++nt) {
        bf8 bfr = *reinterpret_cast<const bf8*>(wproj + (size_t)(nt * 16 + lr) * 96 + kc * 32 + lg * 8);
        acc[nt] = __builtin_amdgcn_mfma_f32_16x16x32_bf16(afr, bfr, acc[nt], 0, 0, 0);
      }
    }
    float pbv[6], gv[6], bv[6];
#pragma unroll
    for (int nt = 0; nt < 6; ++nt) {
      int col = nt * 16 + lr;
      pbv[nt] = proj_b[col];
      gv[nt] = ln1s[col];
      bv[nt] = ln1b[col];
    }
#pragma unroll
    for (int r = 0; r < 4; ++r) {
      int q = mt * 16 + lg * 4 + r;
      if (q >= 49) continue;           // uniform across the 16 lr lanes
      size_t rb = ((size_t)b * LROW + gidx[q]) * CD;
      float v[6];
#pragma unroll
      for (int nt = 0; nt < 6; ++nt)
        v[nt] = acc[nt][r] + pbv[nt] + xin[rb + nt * 16 + lr];
      float s = ((v[0] + v[1]) + (v[2] + v[3])) + (v[4] + v[5]);
      s += __shfl_xor(s, 1); s += __shfl_xor(s, 2);
      s += __shfl_xor(s, 4); s += __shfl_xor(s, 8);
      float mu = s * (1.f / 96.f);
      float d[6];
      float qs = 0.f;
#pragma unroll
      for (int nt = 0; nt < 6; ++nt) { d[nt] = v[nt] - mu; qs += d[nt] * d[nt]; }
      qs += __shfl_xor(qs, 1); qs += __shfl_xor(qs, 2);
      qs += __shfl_xor(qs, 4); qs += __shfl_xor(qs, 8);
      float rstd = rsqrtf(qs * (1.f / 96.f) + 1e-6f);
#pragma unroll
      for (int nt = 0; nt < 6; ++nt) {
        x1[rb + nt * 16 + lr] = v[nt];
        hb2[rb + nt * 16 + lr] = f2bf(d[nt] * rstd * gv[nt] + bv[nt]);
      }
    }
  }
}

// ---------------- qkv GEMM (bf16 MFMA); V stored tile-blocked [bh][49][32][64] ----------------
__global__ __launch_bounds__(256) void qkv_mfma_kernel(
    const short* __restrict__ A, const short* __restrict__ Bt,
    const float* __restrict__ bias,
    short* __restrict__ qb, short* __restrict__ kb, short* __restrict__ vtb) {
  __shared__ __align__(16) short As[2][128 * 32];
  __shared__ __align__(16) short Bs[2][64 * 32];
  int tid = threadIdx.x, lane = tid & 63, wid = tid >> 6;
  int lr = lane & 15, lg = lane >> 4;
  int m0 = blockIdx.x * 128, n0 = blockIdx.y * 64;
  const int K = 96;

  f32x4 acc[2][4];
#pragma unroll
  for (int i = 0; i < 2; ++i)
#pragma unroll
    for (int j = 0; j < 4; ++j) acc[i][j] = (f32x4){0.f, 0.f, 0.f, 0.f};

  auto stage = [&](int bf, int ks) {
    int k0 = ks * 32;
#pragma unroll
    for (int p = 0; p < 2; ++p) {
      int idx = tid + p * 256;
      GLOAD_LDS16(A + (size_t)(m0 + (idx >> 2)) * K + k0 + (idx & 3) * 8,
                  &As[bf][idx * 8]);
    }
    GLOAD_LDS16(Bt + (size_t)(n0 + (tid >> 2)) * K + k0 + (tid & 3) * 8,
                &Bs[bf][tid * 8]);
  };

  stage(0, 0);
  __syncthreads();
  int buf = 0;
  for (int ks = 0; ks < 3; ++ks) {
    if (ks + 1 < 3) stage(buf ^ 1, ks + 1);
    bf8 bfr[4], afr[2];
#pragma unroll
    for (int ni = 0; ni < 4; ++ni)
      bfr[ni] = *reinterpret_cast<const bf8*>(&Bs[buf][(ni * 16 + lr) * 32 + lg * 8]);
#pragma unroll
    for (int mi = 0; mi < 2; ++mi)
      afr[mi] = *reinterpret_cast<const bf8*>(&As[buf][(wid * 32 + mi * 16 + lr) * 32 + lg * 8]);
    __builtin_amdgcn_s_setprio(1);
#pragma unroll
    for (int mi = 0; mi < 2; ++mi)
#pragma unroll
      for (int ni = 0; ni < 4; ++ni)
        acc[mi][ni] = __builtin_amdgcn_mfma_f32_16x16x32_bf16(afr[mi], bfr[ni], acc[mi][ni], 0, 0, 0);
    __builtin_amdgcn_s_setprio(0);
    __syncthreads();
    buf ^= 1;
  }

#pragma unroll
  for (int mi = 0; mi < 2; ++mi)
#pragma unroll
    for (int ni = 0; ni < 4; ++ni)
#pragma unroll
      for (int r = 0; r < 4; ++r) {
        int mrow = m0 + wid * 32 + mi * 16 + lg * 4 + r;
        int n = n0 + ni * 16 + lr;
        if (n < 288) {
          float v = acc[mi][ni][r] + bias[n];
          int sec = n / 96, within = n % 96;
          int hh = within >> 5, dd = within & 31;
          int bb = mrow / LROW, nn = mrow - bb * LROW;
          size_t bh = (size_t)bb * 3 + hh;
          if (sec == 0)      qb[(bh * LROW + nn) * 32 + dd] = f2bf(v * (QSCALE * LOG2E));
          else if (sec == 1) kb[(bh * LROW + nn) * 32 + dd] = f2bf(v);
          else               vtb[((bh * 49 + (nn >> 6)) * 32 + dd) * 64 + (nn & 63)] = f2bf(v);
        }
      }
}

// ---------------- flash attention v9: tile-blocked V (contiguous 4KB/tile), l via ones-MFMA ----------------
// grid (49, 12, 6). vtb layout [bh][kt][32][64]: V fragment loads hit adjacent, fully-consumed lines.
__global__ __launch_bounds__(128) void flash_mfma_kernel(
    const short* __restrict__ qb, const short* __restrict__ kb,
    const short* __restrict__ vtb,
    short* __restrict__ pOb, float* __restrict__ pl) {
  __shared__ __align__(16) short Pt[2][2][16][72];  // [wave][g][q][kv]; 144B rows (no aliasing)
  int tid = threadIdx.x, lane = tid & 63, wid = tid >> 6;
  int lr = lane & 15, lg = lane >> 4;
  int bh = blockIdx.y, s = blockIdx.z;
  int q0 = blockIdx.x * 64 + wid * 32;
  const short* qbb = qb + (size_t)bh * LROW * 32;
  const short* kbase = kb + (size_t)bh * LROW * 32 + lr * 32 + lg * 8;
  const short* vbase = vtb + (size_t)bh * 49 * 2048 + lr * 64 + lg * 8;  // tile t at +t*2048

  bf8 qf0 = *reinterpret_cast<const bf8*>(qbb + (size_t)(q0 + lr) * 32 + lg * 8);
  bf8 qf1 = *reinterpret_cast<const bf8*>(qbb + (size_t)(q0 + 16 + lr) * 32 + lg * 8);

  const bf8 onesf = {16256, 16256, 16256, 16256, 16256, 16256, 16256, 16256};  // bf16 1.0

  f32x4 O00 = {0.f,0.f,0.f,0.f}, O01 = {0.f,0.f,0.f,0.f};
  f32x4 O10 = {0.f,0.f,0.f,0.f}, O11 = {0.f,0.f,0.f,0.f};
  f32x4 La0 = {0.f,0.f,0.f,0.f}, La1 = {0.f,0.f,0.f,0.f};  // l accumulators (all rows equal)

  const int tbl[7] = {0, 9, 17, 25, 33, 41, 49};
  int t0 = tbl[s], t1 = tbl[s + 1];

  bf8 kA[4], vA[4], kB[4], vB[4];

  auto loadt = [&](bf8 (&Kf)[4], bf8 (&Vf)[4], int kt) {
    const short* kp = kbase + (size_t)kt * 2048;
#pragma unroll
    for (int t = 0; t < 4; ++t) Kf[t] = *reinterpret_cast<const bf8*>(kp + t * 512);
    const short* vp = vbase + (size_t)kt * 2048;   // rows d=lr; +1024 => d=16+lr
#pragma unroll
    for (int c = 0; c < 2; ++c) {
      Vf[c]     = *reinterpret_cast<const bf8*>(vp + c * 32);
      Vf[2 + c] = *reinterpret_cast<const bf8*>(vp + 1024 + c * 32);
    }
  };

  auto body = [&](bf8 (&Kf)[4], bf8 (&Vf)[4]) {
    f32x4 z = {0.f, 0.f, 0.f, 0.f};
#pragma unroll
    for (int g = 0; g < 2; ++g) {
      bf8 qf = g ? qf1 : qf0;
      f32x4 St[4];
      __builtin_amdgcn_s_setprio(1);
#pragma unroll
      for (int t = 0; t < 4; ++t)
        St[t] = __builtin_amdgcn_mfma_f32_16x16x32_bf16(Kf[t], qf, z, 0, 0, 0);
      __builtin_amdgcn_s_setprio(0);
#pragma unroll
      for (int t = 0; t < 4; ++t) {
        float p0 = fast_exp2(St[t][0]);
        float p1 = fast_exp2(St[t][1]);
        float p2 = fast_exp2(St[t][2]);
        float p3 = fast_exp2(St[t][3]);
        uint2 w;
        w.x = pack_bf2(p0, p1);
        w.y = pack_bf2(p2, p3);
        *reinterpret_cast<uint2*>(&Pt[wid][g][lr][t * 16 + lg * 4]) = w;
      }
    }
    __builtin_amdgcn_s_setprio(1);
#pragma unroll
    for (int g = 0; g < 2; ++g) {
      f32x4& Oh0 = g ? O10 : O00;
      f32x4& Oh1 = g ? O11 : O01;
      f32x4& La  = g ? La1 : La0;
#pragma unroll
      for (int c = 0; c < 2; ++c) {
        bf8 pbf = *reinterpret_cast<const bf8*>(&Pt[wid][g][lr][c * 32 + lg * 8]);
        Oh0 = __builtin_amdgcn_mfma_f32_16x16x32_bf16(Vf[c], pbf, Oh0, 0, 0, 0);
        Oh1 = __builtin_amdgcn_mfma_f32_16x16x32_bf16(Vf[2 + c], pbf, Oh1, 0, 0, 0);
        La  = __builtin_amdgcn_mfma_f32_16x16x32_bf16(onesf, pbf, La, 0, 0, 0);
      }
    }
    __builtin_amdgcn_s_setprio(0);
  };

  loadt(kA, vA, t0);
  int kt = t0;
  for (; kt + 2 <= t1 - 1; kt += 2) {
    loadt(kB, vB, kt + 1);
    body(kA, vA);
    loadt(kA, vA, kt + 2);
    body(kB, vB);
  }
  if (kt < t1 - 1) {
    loadt(kB, vB, kt + 1);
    body(kA, vA);
    body(kB, vB);
  } else {
    body(kA, vA);
  }

  // bf16 unnormalized partials; lane (lr,lg) holds d = lg*4+r (+16) for q = q0(+16)+lr
  size_t rbase = (size_t)(s * 12 + bh) * LROW;
  size_t r0 = (rbase + q0 + lr) * 32;
  size_t r1 = (rbase + q0 + 16 + lr) * 32;
  uint2 w;
  w.x = pack_bf2r(O00[0], O00[1]); w.y = pack_bf2r(O00[2], O00[3]);
  *reinterpret_cast<uint2*>(&pOb[r0 + lg * 4]) = w;
  w.x = pack_bf2r(O01[0], O01[1]); w.y = pack_bf2r(O01[2], O01[3]);
  *reinterpret_cast<uint2*>(&pOb[r0 + 16 + lg * 4]) = w;
  w.x = pack_bf2r(O10[0], O10[1]); w.y = pack_bf2r(O10[2], O10[3]);
  *reinterpret_cast<uint2*>(&pOb[r1 + lg * 4]) = w;
  w.x = pack_bf2r(O11[0], O11[1]); w.y = pack_bf2r(O11[2], O11[3]);
  *reinterpret_cast<uint2*>(&pOb[r1 + 16 + lg * 4]) = w;
  if (lg == 0) {
    pl[rbase + q0 + lr] = La0[0];
    pl[rbase + q0 + 16 + lr] = La1[0];
  }
}

// ---------------- out-proj GEMM with fused 6-split merge (A-stage) + residual + LN2 ----------------
__global__ __launch_bounds__(256) void gemm_out_merge_ln_kernel(
    const short* __restrict__ pOb, const float* __restrict__ pl,
    const short* __restrict__ Bt,
    const float* __restrict__ bias, const float* __restrict__ res,
    const float* __restrict__ g2, const float* __restrict__ b2,
    float* __restrict__ x2, short* __restrict__ hb3) {
  __shared__ __align__(16) short As[128][104];   // merged bf16 A, padded rows
  __shared__ __align__(16) short Bs[2][96 * 32];
  int tid = threadIdx.x, lane = tid & 63, wid = tid >> 6;
  int lr = lane & 15, lg = lane >> 4;
  int m0 = blockIdx.x * 128;
  const int K = 96;
  const int NR = 12 * LROW;

  // ---- merge-stage A: thread handles (row, head) pairs ----
  for (int pi = tid; pi < 384; pi += 256) {
    int rloc = pi / 3, h = pi % 3;
    int grow = m0 + rloc;
    int bb = grow / LROW, q = grow - bb * LROW;
    size_t pbase = ((size_t)(bb * 3 + h)) * LROW + q;
    float l = 0.f;
#pragma unroll
    for (int s = 0; s < 6; ++s) l += pl[(size_t)s * NR + pbase];
    float invl = 1.f / l;
    float o[32];
#pragma unroll
    for (int d = 0; d < 32; ++d) o[d] = 0.f;
#pragma unroll
    for (int s = 0; s < 6; ++s) {
      const uint4* p4 = reinterpret_cast<const uint4*>(pOb + ((size_t)s * NR + pbase) * 32);
#pragma unroll
      for (int u = 0; u < 4; ++u) {
        uint4 v = p4[u];
        unsigned wd0 = v.x, wd1 = v.y, wd2 = v.z, wd3 = v.w;
        o[u*8+0] += __uint_as_float(wd0 << 16);
        o[u*8+1] += __uint_as_float(wd0 & 0xffff0000u);
        o[u*8+2] += __uint_as_float(wd1 << 16);
        o[u*8+3] += __uint_as_float(wd1 & 0xffff0000u);
        o[u*8+4] += __uint_as_float(wd2 << 16);
        o[u*8+5] += __uint_as_float(wd2 & 0xffff0000u);
        o[u*8+6] += __uint_as_float(wd3 << 16);
        o[u*8+7] += __uint_as_float(wd3 & 0xffff0000u);
      }
    }
    short* dst = &As[rloc][h * 32];
#pragma unroll
    for (int u2 = 0; u2 < 4; ++u2) {
      uint4 w;
      w.x = pack_bf2r(o[u2*8+0]*invl, o[u2*8+1]*invl);
      w.y = pack_bf2r(o[u2*8+2]*invl, o[u2*8+3]*invl);
      w.z = pack_bf2r(o[u2*8+4]*invl, o[u2*8+5]*invl);
      w.w = pack_bf2r(o[u2*8+6]*invl, o[u2*8+7]*invl);
      *reinterpret_cast<uint4*>(dst + u2 * 8) = w;
    }
  }

  f32x4 acc[2][6];
#pragma unroll
  for (int i = 0; i < 2; ++i)
#pragma unroll
    for (int j = 0; j < 6; ++j) acc[i][j] = (f32x4){0.f, 0.f, 0.f, 0.f};

  auto stageB = [&](int bf, int ks) {
    int k0 = ks * 32;
    for (int l = tid; l < 384; l += 256) {
      GLOAD_LDS16(Bt + (size_t)(l >> 2) * K + k0 + (l & 3) * 8,
                  &Bs[bf][l * 8]);
    }
  };

  stageB(0, 0);
  __syncthreads();   // drains merge ds_writes + GLOAD vmcnt
  int buf = 0;
  for (int ks = 0; ks < 3; ++ks) {
    if (ks + 1 < 3) stageB(buf ^ 1, ks + 1);
    bf8 bfr[6], afr[2];
#pragma unroll
    for (int ni = 0; ni < 6; ++ni)
      bfr[ni] = *reinterpret_cast<const bf8*>(&Bs[buf][(ni * 16 + lr) * 32 + lg * 8]);
#pragma unroll
    for (int mi = 0; mi < 2; ++mi)
      afr[mi] = *reinterpret_cast<const bf8*>(&As[wid * 32 + mi * 16 + lr][ks * 32 + lg * 8]);
    __builtin_amdgcn_s_setprio(1);
#pragma unroll
    for (int mi = 0; mi < 2; ++mi)
#pragma unroll
      for (int ni = 0; ni < 6; ++ni)
        acc[mi][ni] = __builtin_amdgcn_mfma_f32_16x16x32_bf16(afr[mi], bfr[ni], acc[mi][ni], 0, 0, 0);
    __builtin_amdgcn_s_setprio(0);
    __syncthreads();
    buf ^= 1;
  }

  float bb[6], gv[6], bv[6];
#pragma unroll
  for (int ni = 0; ni < 6; ++ni) {
    int col = ni * 16 + lr;
    bb[ni] = bias[col];
    gv[ni] = g2[col];
    bv[ni] = b2[col];
  }
#pragma unroll
  for (int mi = 0; mi < 2; ++mi)
#pragma unroll
    for (int r = 0; r < 4; ++r) {
      int row = m0 + wid * 32 + mi * 16 + lg * 4 + r;
      size_t rb = (size_t)row * CD;
      float v[6];
#pragma unroll
      for (int ni = 0; ni < 6; ++ni)
        v[ni] = acc[mi][ni][r] + bb[ni] + res[rb + ni * 16 + lr];
      float s = ((v[0] + v[1]) + (v[2] + v[3])) + (v[4] + v[5]);
      s += __shfl_xor(s, 1); s += __shfl_xor(s, 2);
      s += __shfl_xor(s, 4); s += __shfl_xor(s, 8);
      float mu = s * (1.f / 96.f);
      float d[6];
      float qs = 0.f;
#pragma unroll
      for (int ni = 0; ni < 6; ++ni) { d[ni] = v[ni] - mu; qs += d[ni] * d[ni]; }
      qs += __shfl_xor(qs, 1); qs += __shfl_xor(qs, 2);
      qs += __shfl_xor(qs, 4); qs += __shfl_xor(qs, 8);
      float rstd = rsqrtf(qs * (1.f / 96.f) + 1e-6f);
#pragma unroll
      for (int ni = 0; ni < 6; ++ni) {
        x2[rb + ni * 16 + lr] = v[ni];
        hb3[rb + ni * 16 + lr] = f2bf(d[ni] * rstd * gv[ni] + bv[ni]);
      }
    }
}

// ---------------- fused MLP: fc1 (gelu) -> LDS -> fc2 (+bias+residual) -> out ----------------
__global__ __launch_bounds__(256) void mlp_kernel(
    const short* __restrict__ hb3, const short* __restrict__ wfc1,
    const float* __restrict__ fc1_b, const short* __restrict__ wfc2,
    const float* __restrict__ fc2_b, const float* __restrict__ resid,
    float* __restrict__ outx) {
  __shared__ __align__(16) short Ah[64][104];
  __shared__ __align__(16) short T[64][392];
  int tid = threadIdx.x, lane = tid & 63, wid = tid >> 6;
  int lr = lane & 15, lg = lane >> 4;
  int m0 = blockIdx.x * 64;

  for (int i = tid; i < 768; i += 256) {
    int row = i / 12, c8 = i % 12;
    uint4 v = *reinterpret_cast<const uint4*>(hb3 + (size_t)(m0 + row) * 96 + c8 * 8);
    *reinterpret_cast<uint4*>(&Ah[row][c8 * 8]) = v;
  }
  __syncthreads();

  // ---- fc1: M=64, N-strip=96 per wave, K=96 ----
  {
    f32x4 acc[4][6];
#pragma unroll
    for (int i = 0; i < 4; ++i)
#pragma unroll
      for (int j = 0; j < 6; ++j) acc[i][j] = (f32x4){0.f, 0.f, 0.f, 0.f};
#pragma unroll
    for (int kc = 0; kc < 3; ++kc) {
      bf8 bfr[6], afr[4];
#pragma unroll
      for (int nt = 0; nt < 6; ++nt)
        bfr[nt] = *reinterpret_cast<const bf8*>(wfc1 + (size_t)(wid * 96 + nt * 16 + lr) * 96 + kc * 32 + lg * 8);
#pragma unroll
      for (int mi = 0; mi < 4; ++mi)
        afr[mi] = *reinterpret_cast<const bf8*>(&Ah[mi * 16 + lr][kc * 32 + lg * 8]);
      __builtin_amdgcn_s_setprio(1);
#pragma unroll
      for (int mi = 0; mi < 4; ++mi)
#pragma unroll
        for (int nt = 0; nt < 6; ++nt)
          acc[mi][nt] = __builtin_amdgcn_mfma_f32_16x16x32_bf16(afr[mi], bfr[nt], acc[mi][nt], 0, 0, 0);
      __builtin_amdgcn_s_setprio(0);
    }
#pragma unroll
    for (int nt = 0; nt < 6; ++nt) {
      float b1 = fc1_b[wid * 96 + nt * 16 + lr];
      int col = wid * 96 + nt * 16 + lr;
#pragma unroll
      for (int mi = 0; mi < 4; ++mi)
#pragma unroll
        for (int r = 0; r < 4; ++r)
          T[mi * 16 + lg * 4 + r][col] = f2bf(gelu_f(acc[mi][nt][r] + b1));
    }
  }
  __syncthreads();

  // ---- fc2: rows [w*16,(w+1)*16), N=96, K=384 ----
  {
    f32x4 a2[6];
#pragma unroll
    for (int j = 0; j < 6; ++j) a2[j] = (f32x4){0.f, 0.f, 0.f, 0.f};
#pragma unroll
    for (int kc = 0; kc < 12; ++kc) {
      bf8 afr2 = *reinterpret_cast<const bf8*>(&T[wid * 16 + lr][kc * 32 + lg * 8]);
      bf8 bfr2[6];
#pragma unroll
      for (int nt = 0; nt < 6; ++nt)
        bfr2[nt] = *reinterpret_cast<const bf8*>(wfc2 + (size_t)(nt * 16 + lr) * 384 + kc * 32 + lg * 8);
      __builtin_amdgcn_s_setprio(1);
#pragma unroll
      for (int nt = 0; nt < 6; ++nt)
        a2[nt] = __builtin_amdgcn_mfma_f32_16x16x32_bf16(afr2, bfr2[nt], a2[nt], 0, 0, 0);
      __builtin_amdgcn_s_setprio(0);
    }
#pragma unroll
    for (int nt = 0; nt < 6; ++nt) {
      float b2v = fc2_b[nt * 16 + lr];
#pragma unroll
      for (int r = 0; r < 4; ++r) {
        int row = m0 + wid * 16 + lg * 4 + r;
        size_t idx = (size_t)row * CD + nt * 16 + lr;
        outx[idx] = a2[nt][r] + b2v + resid[idx];
      }
    }
  }
}

extern "C" void kernel_launch(void* const* d_in, const int* in_sizes, int n_in,
                              void* d_out, int out_size, void* d_ws, size_t ws_size,
                              hipStream_t stream) {
  const float* x      = (const float*)d_in[0];
  const int*   Hp     = (const int*)d_in[1];
  const int*   Wp     = (const int*)d_in[2];
  const float* n1s    = (const float*)d_in[3];
  const float* n1b    = (const float*)d_in[4];
  const float* qkv_w  = (const float*)d_in[5];
  const float* qkv_b  = (const float*)d_in[6];
  const float* proj_w = (const float*)d_in[7];
  const float* proj_b = (const float*)d_in[8];
  const float* ln1s   = (const float*)d_in[9];
  const float* ln1b   = (const float*)d_in[10];
  const float* qkv2_w = (const float*)d_in[11];
  const float* qkv2_b = (const float*)d_in[12];
  const float* out_w  = (const float*)d_in[13];
  const float* out_b  = (const float*)d_in[14];
  const float* ln2s   = (const float*)d_in[15];
  const float* ln2b   = (const float*)d_in[16];
  const float* fc1_w  = (const float*)d_in[17];
  const float* fc1_b  = (const float*)d_in[18];
  const float* fc2_w  = (const float*)d_in[19];
  const float* fc2_b  = (const float*)d_in[20];

  float* wsf = (float*)d_ws;
  const size_t U = (size_t)4 * LROW * CD;  // 1,204,224
  float* x1   = wsf;                           // [0,U) fp32 residual (win out)
  short* hb   = (short*)(wsf + 2 * U);         // [2U,2.5U) bf16 LN1 out (dead before flash)
  short* qb   = (short*)(wsf + 4 * U + U / 2); // [4.5U,5U)
  short* kb   = qb + U;                        // [5U,5.5U)
  short* vtb  = kb + U;                        // [5.5U,6U); 12*49*2048 shorts (tile-blocked)
  short* wall = (short*)(wsf + 6 * U);         // contiguous bf16 weights, 165888 shorts
  short* wqkv = wall;                          // 320*96
  short* wout = wqkv + 320 * 96;               // 128*96
  short* wfc1 = wout + 128 * 96;               // 384*96
  short* wfc2 = wfc1 + 384 * 96;               // 128*384
  short* wwin = wfc2 + 128 * 384;              // 288*96
  short* wproj = wwin + 288 * 96;              // 96*96
  short* hb2  = (short*)(wsf + 6 * U + 82944); // bf16 LN-tb1 out (U shorts)
  // flash partials overlay [U,4U): pOb bf16 6 splits (3U floats); pl at [4U,4.2U)
  short* pOb  = (short*)(wsf + U);             // 6 * 12*LROW*32 shorts = 3U floats
  float* pl   = wsf + 4 * U;                   // 6 * 12*LROW floats
  // post-flash outputs live OUTSIDE the pOb overlay (qb/kb/vtb dead after flash):
  float* x2f  = (float*)qb;                    // U floats over [4.5U,5.5U)
  short* hb3  = vtb;                           // U shorts, LN2 out bf16
  float* outx = (float*)d_out;

  const int M = 4 * LROW;  // 12544

  cvt_all_kernel<<<(165888 + 255) / 256, 256, 0, stream>>>(
      qkv2_w, out_w, fc1_w, fc2_w, qkv_w, proj_w, wall, Hp, Wp, outx + U);

  ln_kernel<<<M / 8, 256, 0, stream>>>(x, n1s, n1b, hb, M);
  win_attn_kernel<<<256, 512, 0, stream>>>(hb, x, wwin, qkv_b, wproj, proj_b,
                                           ln1s, ln1b, x1, hb2);
  qkv_mfma_kernel<<<dim3(M / 128, 5), 256, 0, stream>>>(hb2, wqkv, qkv2_b, qb, kb, vtb);
  flash_mfma_kernel<<<dim3(49, 12, 6), 128, 0, stream>>>(qb, kb, vtb, pOb, pl);
  gemm_out_merge_ln_kernel<<<M / 128, 256, 0, stream>>>(pOb, pl, wout, out_b, x1,
                                                        ln2s, ln2b, x2f, hb3);
  mlp_kernel<<<M / 64, 256, 0, stream>>>(hb3, wfc1, fc1_b, wfc2, fc2_b, x2f, outx);
}